// Round 15
// baseline (592.035 us; speedup 1.0000x reference)
//
#include <hip/hip_runtime.h>
#include <hip/hip_bf16.h>
#include <stdint.h>

#define TT 2048
#define BB 8
#define DD 1024
#define FF 2048   // 4*H*N
#define HN 512
#define KB_CNT 32         // DD/32 k-blocks
#define ROWB 128          // bytes per (row, k-block): 8 slots * 16B
#define MSTRIDE 4096      // bytes per row in split layout = KB_CNT*ROWB

typedef float f32x4 __attribute__((ext_vector_type(4)));
typedef float f32x2 __attribute__((ext_vector_type(2)));
typedef _Float16 h8_t __attribute__((ext_vector_type(8)));

#define CC   2.88539008f    // 2/ln2
#define SQC  1.69864360f    // sqrt(2/ln2)

// ---------- fast math helpers ----------
__device__ __forceinline__ float fexp2(float x){ return __builtin_amdgcn_exp2f(x); }
__device__ __forceinline__ float frcp(float x){ return __builtin_amdgcn_rcpf(x); }
__device__ __forceinline__ float fsqrt_(float x){ return __builtin_amdgcn_sqrtf(x); }
__device__ __forceinline__ float fast_sigmoid(float x){
    return frcp(1.0f + fexp2(-1.44269504f * x));
}

// DPP butterfly add (old=0, bound_ctrl; fetches confined to 16-lane DPP row)
template<int CTRL>
__device__ __forceinline__ float dppadd(float v){
    int x = __builtin_amdgcn_update_dpp(0, __float_as_int(v), CTRL, 0xf, 0xf, true);
    return v + __int_as_float(x);
}
// sum over 16-lane group
__device__ __forceinline__ float reduce16(float v){
    v = dppadd<0xB1>(v);   // + lane^1
    v = dppadd<0x4E>(v);   // + lane^2
    v = dppadd<0x141>(v);  // row_half_mirror: + lane^4
    v = dppadd<0x140>(v);  // row_mirror:      + lane^8
    return v;
}

// ---------- split fp32 -> (hi,lo) fp16 ----------
__device__ __forceinline__ void split8(const float* f, int4& hi, int4& lo){
    union { _Float16 h[8]; int4 i; } a, c;
    #pragma unroll
    for (int u = 0; u < 8; ++u) {
        _Float16 h = (_Float16)f[u];
        a.h[u] = h;
        c.h[u] = (_Float16)(f[u] - (float)h);
    }
    hi = a.i; lo = c.i;
}

// ---------- Weff = [Wk;Wv;Wq;Wb] * W_in, fused concat, 64x64 tiles ----------
__global__ __launch_bounds__(256)
void gemm_f32c(const float* __restrict__ s0, const float* __restrict__ s1,
               const float* __restrict__ s2, const float* __restrict__ s3,
               const float* __restrict__ B, float* __restrict__ C)
{
    __shared__ __align__(16) float As[16][68];
    __shared__ __align__(16) float Bs[16][72];
    const int tid = threadIdx.x;
    const int tx = tid & 15, ty = tid >> 4;
    const int n0 = blockIdx.x * 64, m0 = blockIdx.y * 64;
    float acc[4][4] = {};

    const int arow = tid >> 2, ac4 = (tid & 3) << 2;
    const int f = m0 + arow;
    const float* asrc = ((f < 512) ? s0 : (f < 1024) ? s1 : (f < 1536) ? s2 : s3)
                        + (size_t)(f & 511) * DD + ac4;
    const int bk = tid >> 4, bc = tid & 15;

    for (int k0 = 0; k0 < DD; k0 += 16) {
        float4 av = *(const float4*)(asrc + k0);
        As[ac4+0][arow] = av.x; As[ac4+1][arow] = av.y;
        As[ac4+2][arow] = av.z; As[ac4+3][arow] = av.w;
        float4 bv = *(const float4*)&B[(size_t)(k0 + bk) * DD + n0 + bc * 4];
        int p = bc + (bc >> 3);
        *(float4*)&Bs[bk][p << 2] = bv;
        __syncthreads();
        #pragma unroll
        for (int kk = 0; kk < 16; ++kk) {
            float a[4], b[4];
            *(float4*)&a[0] = *(const float4*)&As[kk][ty * 4];
            int p2 = tx + (tx >> 3);
            *(float4*)&b[0] = *(const float4*)&Bs[kk][p2 << 2];
            #pragma unroll
            for (int i = 0; i < 4; ++i)
                #pragma unroll
                for (int j = 0; j < 4; ++j)
                    acc[i][j] = __builtin_fmaf(a[i], b[j], acc[i][j]);
        }
        __syncthreads();
    }
    #pragma unroll
    for (int ii = 0; ii < 4; ++ii) {
        float4 v;
        v.x = acc[ii][0]; v.y = acc[ii][1]; v.z = acc[ii][2]; v.w = acc[ii][3];
        *(float4*)&C[(size_t)(m0 + ty * 4 + ii) * DD + n0 + tx * 4] = v;
    }
}

// ---------- fp32 -> split fp16 pre-swizzled ----------
__global__ __launch_bounds__(256)
void wconv(const float* __restrict__ W, char* __restrict__ out)
{
    int gid = blockIdx.x * 256 + threadIdx.x;
    int n  = gid >> 6;
    int kh = gid & 63;
    const float* src = W + (size_t)n * DD + kh * 16;
    float f[16];
    *(float4*)&f[0]  = *(const float4*)(src + 0);
    *(float4*)&f[4]  = *(const float4*)(src + 4);
    *(float4*)&f[8]  = *(const float4*)(src + 8);
    *(float4*)&f[12] = *(const float4*)(src + 12);
    int4 hi0, hi1, lo0, lo1;
    split8(&f[0], hi0, lo0);
    split8(&f[8], hi1, lo1);
    int kb = kh >> 1, c0 = (kh & 1) * 2, rs = n & 7;
    char* dst = out + (size_t)n * MSTRIDE + kb * ROWB;
    *(int4*)(dst + (((c0+0) ^ rs) * 16)) = hi0;
    *(int4*)(dst + (((c0+1) ^ rs) * 16)) = hi1;
    *(int4*)(dst + (((c0+4) ^ rs) * 16)) = lo0;
    *(int4*)(dst + (((c0+5) ^ rs) * 16)) = lo1;
}

// Epilogue packet layout (8192B per row m, 512B per h):
//   kq: [k0 k1 q0 q1] x16 -> k_j at (j>>1)*16+(j&1)*4, q_j at +8
//   vb: [v b] x32 at +256  -> v_i at 256+i*8 (SQC*v), b_i at 256+i*8+4
#define EPI_STORE(Cb, rbase, reg, hh, idx, blk, v, bb) { \
    char* rowp = (char*)(Cb) + (size_t)((rbase) + (reg)) * 8192 + (hh) * 512; \
    if ((blk) == 0)      *(float*)(rowp + ((idx) >> 1) * 16 + ((idx) & 1) * 4) = (v); \
    else if ((blk) == 2) *(float*)(rowp + ((idx) >> 1) * 16 + 8 + ((idx) & 1) * 4) = (v); \
    else if ((blk) == 1) *(float*)(rowp + 256 + (idx) * 8) = SQC * (v); \
    else                 *(float*)(rowp + 256 + (idx) * 8 + 4) = CC * fast_sigmoid((v) + (bb)); \
}

// ---------- 256x256 dbuf MFMA GEMM (8 waves), 3-pass MFMA ordering ----------
__global__ __launch_bounds__(512, 1)
void gemm_mfma8(const char* __restrict__ Axp, const char* __restrict__ Wsp,
                float* __restrict__ C, const float* __restrict__ bias)
{
    extern __shared__ char ldsb[];   // 131072
    const int tid  = threadIdx.x;
    const int wave = tid >> 6, lane = tid & 63;
    const int wm = wave >> 2, wn = wave & 3;        // 2 x 4 waves
    const int nt = blockIdx.x & 7, mt = blockIdx.x >> 3;
    const int m0 = mt * 256, n0 = nt * 256;

    f32x4 acc[8][4] = {};

    const char* aT = Axp + (size_t)(m0 + wave * 32 + (lane >> 3)) * MSTRIDE + (lane & 7) * 16;
    const char* bT = Wsp + (size_t)(n0 + wave * 32 + (lane >> 3)) * MSTRIDE + (lane & 7) * 16;
    const int ldst = (wave * 32) * 128;

    const int fl = lane & 15, fh = lane >> 4;
    const int shi = (fh ^ (fl & 7)) * 16;
    const int slo = ((fh + 4) ^ (fl & 7)) * 16;

    {
        char* L = ldsb;
        #pragma unroll
        for (int g = 0; g < 4; ++g)
            __builtin_amdgcn_global_load_lds(
                (const __attribute__((address_space(1))) uint32_t*)(aT + (size_t)g * 8 * MSTRIDE),
                (__attribute__((address_space(3))) uint32_t*)(L + ldst + g * 1024),
                16, 0, 0);
        #pragma unroll
        for (int g = 0; g < 4; ++g)
            __builtin_amdgcn_global_load_lds(
                (const __attribute__((address_space(1))) uint32_t*)(bT + (size_t)g * 8 * MSTRIDE),
                (__attribute__((address_space(3))) uint32_t*)(L + 32768 + ldst + g * 1024),
                16, 0, 0);
    }

    union u8 { int4 i; h8_t h; };
    u8 Ah[4], Al[4], Bh[4], Bl[4];

    for (int t = 0; t < KB_CNT; ++t) {
        char* Lc = ldsb + (t & 1) * 65536;
        char* Ln = ldsb + ((t + 1) & 1) * 65536;
        const bool stg = (t + 1 < KB_CNT);
        const char* aN = aT + ROWB;
        const char* bN = bT + ROWB;

        asm volatile("s_waitcnt vmcnt(0)" ::: "memory");
        __builtin_amdgcn_s_barrier();
        asm volatile("" ::: "memory");

        if (stg) {
            #pragma unroll
            for (int g = 0; g < 4; ++g)
                __builtin_amdgcn_global_load_lds(
                    (const __attribute__((address_space(1))) uint32_t*)(aN + (size_t)g * 8 * MSTRIDE),
                    (__attribute__((address_space(3))) uint32_t*)(Ln + ldst + g * 1024),
                    16, 0, 0);
            #pragma unroll
            for (int g = 0; g < 4; ++g)
                __builtin_amdgcn_global_load_lds(
                    (const __attribute__((address_space(1))) uint32_t*)(bN + (size_t)g * 8 * MSTRIDE),
                    (__attribute__((address_space(3))) uint32_t*)(Ln + 32768 + ldst + g * 1024),
                    16, 0, 0);
        }

        // ---- half 1: fm 0-3 x fn 0-3 ----
        #pragma unroll
        for (int f = 0; f < 4; ++f) {
            const char* base = Lc + (wm * 128 + f * 16 + fl) * 128;
            Ah[f].i = *(const int4*)(base + shi);
            Al[f].i = *(const int4*)(base + slo);
        }
        #pragma unroll
        for (int f = 0; f < 4; ++f) {
            const char* base = Lc + 32768 + (wn * 64 + f * 16 + fl) * 128;
            Bh[f].i = *(const int4*)(base + shi);
            Bl[f].i = *(const int4*)(base + slo);
        }
        __builtin_amdgcn_s_setprio(1);
        #pragma unroll
        for (int i = 0; i < 4; ++i)
            #pragma unroll
            for (int j = 0; j < 4; ++j)
                acc[i][j] = __builtin_amdgcn_mfma_f32_16x16x32_f16(Ah[i].h, Bh[j].h, acc[i][j], 0, 0, 0);
        #pragma unroll
        for (int i = 0; i < 4; ++i)
            #pragma unroll
            for (int j = 0; j < 4; ++j)
                acc[i][j] = __builtin_amdgcn_mfma_f32_16x16x32_f16(Ah[i].h, Bl[j].h, acc[i][j], 0, 0, 0);
        #pragma unroll
        for (int i = 0; i < 4; ++i)
            #pragma unroll
            for (int j = 0; j < 4; ++j)
                acc[i][j] = __builtin_amdgcn_mfma_f32_16x16x32_f16(Al[i].h, Bh[j].h, acc[i][j], 0, 0, 0);
        __builtin_amdgcn_s_setprio(0);

        // ---- half 2: fm 4-7 x fn 0-3 (reuse B frags) ----
        #pragma unroll
        for (int f = 0; f < 4; ++f) {
            const char* base = Lc + (wm * 128 + (f + 4) * 16 + fl) * 128;
            Ah[f].i = *(const int4*)(base + shi);
            Al[f].i = *(const int4*)(base + slo);
        }
        __builtin_amdgcn_s_setprio(1);
        #pragma unroll
        for (int i = 0; i < 4; ++i)
            #pragma unroll
            for (int j = 0; j < 4; ++j)
                acc[i + 4][j] = __builtin_amdgcn_mfma_f32_16x16x32_f16(Ah[i].h, Bh[j].h, acc[i + 4][j], 0, 0, 0);
        #pragma unroll
        for (int i = 0; i < 4; ++i)
            #pragma unroll
            for (int j = 0; j < 4; ++j)
                acc[i + 4][j] = __builtin_amdgcn_mfma_f32_16x16x32_f16(Ah[i].h, Bl[j].h, acc[i + 4][j], 0, 0, 0);
        #pragma unroll
        for (int i = 0; i < 4; ++i)
            #pragma unroll
            for (int j = 0; j < 4; ++j)
                acc[i + 4][j] = __builtin_amdgcn_mfma_f32_16x16x32_f16(Al[i].h, Bh[j].h, acc[i + 4][j], 0, 0, 0);
        __builtin_amdgcn_s_setprio(0);

        aT += ROWB; bT += ROWB;
    }

    const int blk = nt >> 1;   // 0:k 1:v 2:q 3:beta
    if (blk == 0) {
        #pragma unroll
        for (int fm = 0; fm < 8; ++fm)
            #pragma unroll
            for (int hg = 0; hg < 2; ++hg)
                #pragma unroll
                for (int reg = 0; reg < 4; ++reg) {
                    float a = acc[fm][hg*2][reg], c = acc[fm][hg*2+1][reg];
                    float p = __builtin_fmaf(a, a, c * c);
                    p = reduce16(p);
                    float rn = SQC * frcp(fsqrt_(p) + 1e-6f);
                    acc[fm][hg*2][reg]   = a * rn;
                    acc[fm][hg*2+1][reg] = c * rn;
                }
    }

    #pragma unroll
    for (int fm = 0; fm < 8; ++fm) {
        int rbase = m0 + wm * 128 + fm * 16 + fh * 4;
        #pragma unroll
        for (int fn = 0; fn < 4; ++fn) {
            int col = n0 + wn * 64 + fn * 16 + fl;
            int hh  = (col >> 5) & 15;
            int idx = col & 31;
            float bb = (blk == 3) ? bias[col - 3 * HN] : 0.0f;
            #pragma unroll
            for (int reg = 0; reg < 4; ++reg) {
                float v = acc[fm][fn][reg];
                EPI_STORE(C, rbase, reg, hh, idx, blk, v, bb);
            }
        }
    }
}

// ---------- legacy 128x128 MFMA GEMM (fallback) ----------
template<bool PRE>
__global__ __launch_bounds__(256)
void gemm_mfma(const float* __restrict__ A, const char* __restrict__ Axp,
               const char* __restrict__ Wsp,
               float* __restrict__ C, const float* __restrict__ bias)
{
    __shared__ char lds[32768];
    char* Asb = lds;
    char* Bsb = lds + 16384;

    const int tid  = threadIdx.x;
    const int wave = tid >> 6, lane = tid & 63;
    const int wm = wave >> 1, wn = wave & 1;
    const int nt = blockIdx.x & 15, mt = blockIdx.x >> 4;
    const int m0 = mt * 128, n0 = nt * 128;

    f32x4 acc[4][4] = {};

    const int ar = tid >> 1, akh = tid & 1, ars = ar & 7, ac0 = akh * 2;
    const float* asrc = A + (size_t)(m0 + ar) * DD + akh * 16;
    char* awr = Asb + ar * ROWB;

    const char* bsrc_base = Wsp + (size_t)n0 * MSTRIDE;
    const char* asrc_base = Axp + (size_t)m0 * MSTRIDE;

    const int fl = lane & 15, fh = lane >> 4;
    const int shi = (fh ^ (fl & 7)) * 16;
    const int slo = ((fh + 4) ^ (fl & 7)) * 16;
    const int frow = fl * ROWB;

    for (int ks = 0; ks < KB_CNT; ++ks) {
        #pragma unroll
        for (int gg = 0; gg < 4; ++gg) {
            int g = wave * 4 + gg;
            const char* src = bsrc_base + (size_t)(g * 8 + (lane >> 3)) * MSTRIDE
                              + ks * ROWB + (lane & 7) * 16;
            __builtin_amdgcn_global_load_lds(
                (const __attribute__((address_space(1))) uint32_t*)src,
                (__attribute__((address_space(3))) uint32_t*)(Bsb + g * 1024),
                16, 0, 0);
        }
        if (PRE) {
            #pragma unroll
            for (int gg = 0; gg < 4; ++gg) {
                int g = wave * 4 + gg;
                const char* src = asrc_base + (size_t)(g * 8 + (lane >> 3)) * MSTRIDE
                                  + ks * ROWB + (lane & 7) * 16;
                __builtin_amdgcn_global_load_lds(
                    (const __attribute__((address_space(1))) uint32_t*)src,
                    (__attribute__((address_space(3))) uint32_t*)(Asb + g * 1024),
                    16, 0, 0);
            }
        } else {
            const float* ap = asrc + ks * 32;
            float f[16];
            *(float4*)&f[0]  = *(const float4*)(ap + 0);
            *(float4*)&f[4]  = *(const float4*)(ap + 4);
            *(float4*)&f[8]  = *(const float4*)(ap + 8);
            *(float4*)&f[12] = *(const float4*)(ap + 12);
            int4 hi0, hi1, lo0, lo1;
            split8(&f[0], hi0, lo0);
            split8(&f[8], hi1, lo1);
            *(int4*)(awr + (((ac0+0) ^ ars) * 16)) = hi0;
            *(int4*)(awr + (((ac0+1) ^ ars) * 16)) = hi1;
            *(int4*)(awr + (((ac0+4) ^ ars) * 16)) = lo0;
            *(int4*)(awr + (((ac0+5) ^ ars) * 16)) = lo1;
        }
        __syncthreads();

        union { int4 i; h8_t h; } ah[4], al[4], bh[4], bl[4];
        #pragma unroll
        for (int fm = 0; fm < 4; ++fm) {
            const char* base = Asb + (wm * 64 + fm * 16) * ROWB + frow;
            ah[fm].i = *(const int4*)(base + shi);
            al[fm].i = *(const int4*)(base + slo);
        }
        #pragma unroll
        for (int fn = 0; fn < 4; ++fn) {
            const char* base = Bsb + (wn * 64 + fn * 16) * ROWB + frow;
            bh[fn].i = *(const int4*)(base + shi);
            bl[fn].i = *(const int4*)(base + slo);
        }
        #pragma unroll
        for (int fm = 0; fm < 4; ++fm)
            #pragma unroll
            for (int fn = 0; fn < 4; ++fn) {
                acc[fm][fn] = __builtin_amdgcn_mfma_f32_16x16x32_f16(ah[fm].h, bh[fn].h, acc[fm][fn], 0, 0, 0);
                acc[fm][fn] = __builtin_amdgcn_mfma_f32_16x16x32_f16(ah[fm].h, bl[fn].h, acc[fm][fn], 0, 0, 0);
                acc[fm][fn] = __builtin_amdgcn_mfma_f32_16x16x32_f16(al[fm].h, bh[fn].h, acc[fm][fn], 0, 0, 0);
            }
        __syncthreads();
    }

    const int blk = nt >> 2;   // 0:k 1:v 2:q 3:beta
    if (blk == 0) {
        #pragma unroll
        for (int fm = 0; fm < 4; ++fm)
            #pragma unroll
            for (int hg = 0; hg < 2; ++hg)
                #pragma unroll
                for (int reg = 0; reg < 4; ++reg) {
                    float a = acc[fm][hg*2][reg], c = acc[fm][hg*2+1][reg];
                    float p = __builtin_fmaf(a, a, c * c);
                    p = reduce16(p);
                    float rn = SQC * frcp(fsqrt_(p) + 1e-6f);
                    acc[fm][hg*2][reg]   = a * rn;
                    acc[fm][hg*2+1][reg] = c * rn;
                }
    }

    #pragma unroll
    for (int fm = 0; fm < 4; ++fm) {
        int rbase = m0 + wm * 64 + fm * 16 + fh * 4;
        #pragma unroll
        for (int fn = 0; fn < 4; ++fn) {
            int col = n0 + wn * 64 + fn * 16 + fl;
            int hh  = (col >> 5) & 15;
            int idx = col & 31;
            float bb = (blk == 3) ? bias[col - 3 * HN] : 0.0f;
            #pragma unroll
            for (int reg = 0; reg < 4; ++reg) {
                float v = acc[fm][fn][reg];
                EPI_STORE(C, rbase, reg, hh, idx, blk, v, bb);
            }
        }
    }
}

// ---------- sequential recurrence: PF=16 scalarized pipeline ----------
// 256 blocks x 256 threads (1024 waves = 1/SIMD). 16 lanes/row, 2 j/thread.
// Packet: kq dwordx4 [k0 k1 q0 q1] + vb dwordx2 [v~ b~] per step = 2 loads.
// 16 named slots (no arrays -> guaranteed VGPR residency), 32 outstanding
// loads (< 63 cap), per-step store. vmcnt(28): drains steps t and t+1 even
// with 1-3 straggler stores in queue (stores are newest). Depth ~14 steps.
__global__ __launch_bounds__(256, 1)
void recur(const float* __restrict__ proj, const float* __restrict__ S0,
           float* __restrict__ out, float* __restrict__ Sfin)
{
    const int tid = threadIdx.x;
    const int bx  = blockIdx.x;
    const int bh  = bx >> 1;                       // chain 0..127
    const int b   = bh >> 4, h = bh & 15;
    const int i   = ((bx & 1) << 4) + (tid >> 4);  // state row 0..31
    const int jl  = tid & 15;                      // owns j = 2jl, 2jl+1

    f32x2 S;
    {
        const float* s0p = S0 + (size_t)bh * 1024 + i * 32 + 2 * jl;
        S[0] = s0p[0]; S[1] = s0p[1];
    }

    const char* pkq = (const char*)proj + (size_t)b * 8192 + h * 512 + jl * 16;
    const char* pvb = (const char*)proj + (size_t)b * 8192 + h * 512 + 256 + i * 8;
    const size_t rstep = (size_t)BB * 8192;        // 65536 B per t

#define RDECL(p) f32x4 KQ##p; f32x2 VB##p;
    RDECL(0) RDECL(1) RDECL(2) RDECL(3) RDECL(4) RDECL(5) RDECL(6) RDECL(7)
    RDECL(8) RDECL(9) RDECL(10) RDECL(11) RDECL(12) RDECL(13) RDECL(14) RDECL(15)

#define RISSUE(p) \
    asm volatile("global_load_dwordx4 %0, %1, off" : "=v"(KQ##p) : "v"(pkq)); \
    asm volatile("global_load_dwordx2 %0, %1, off" : "=v"(VB##p) : "v"(pvb)); \
    pkq += rstep; pvb += rstep;

    RISSUE(0) RISSUE(1) RISSUE(2) RISSUE(3) RISSUE(4) RISSUE(5) RISSUE(6) RISSUE(7)
    RISSUE(8) RISSUE(9) RISSUE(10) RISSUE(11) RISSUE(12) RISSUE(13) RISSUE(14) RISSUE(15)

    // prime: 32 outstanding -> drain oldest 2 (KQ0, VB0)
    asm volatile("s_waitcnt vmcnt(30)" : "+v"(VB0));
    float cv = VB0[0];
    f32x2 bS = VB0[1] * S;

    float* pout = out + (size_t)b * HN + h * 32 + i;   // stored when jl==0

#define RSTEP(p, pn) { \
    asm volatile("s_waitcnt vmcnt(28)" : "+v"(KQ##p), "+v"(VB##pn)); \
    f32x4 kq = KQ##p; \
    float rr = __builtin_fmaf(S[1], kq[1], S[0] * kq[0]); \
    rr = reduce16(rr); \
    float d = cv - rr; \
    f32x2 k2; k2[0] = kq[0]; k2[1] = kq[1]; \
    f32x2 a = d * k2 + bS; \
    f32x2 e; e[0] = fexp2(a[0]); e[1] = fexp2(a[1]); \
    f32x2 e1 = e + 1.0f; \
    f32x2 r; r[0] = frcp(e1[0]); r[1] = frcp(e1[1]); \
    S = -2.0f * r + 1.0f; \
    float sq = __builtin_fmaf(S[1], kq[3], S[0] * kq[2]); \
    sq = reduce16(sq); \
    if (jl == 0) { float sg = fast_sigmoid(sq); *pout = sq * sq * sg; } \
    pout += BB * HN; \
    cv = VB##pn[0]; \
    bS = VB##pn[1] * S; \
    asm volatile("global_load_dwordx4 %0, %1, off" : "=v"(KQ##p) : "v"(pkq)); \
    asm volatile("global_load_dwordx2 %0, %1, off" : "=v"(VB##p) : "v"(pvb)); \
    pkq += rstep; pvb += rstep; \
}

    for (int t0 = 0; t0 < TT; t0 += 16) {
        RSTEP(0,1)  RSTEP(1,2)   RSTEP(2,3)   RSTEP(3,4)
        RSTEP(4,5)  RSTEP(5,6)   RSTEP(6,7)   RSTEP(7,8)
        RSTEP(8,9)  RSTEP(9,10)  RSTEP(10,11) RSTEP(11,12)
        RSTEP(12,13) RSTEP(13,14) RSTEP(14,15) RSTEP(15,0)
    }

    {
        float* sf = Sfin + (size_t)bh * 1024 + i * 32 + 2 * jl;
        sf[0] = S[0]; sf[1] = S[1];
    }
#undef RSTEP
#undef RISSUE
#undef RDECL
}

extern "C" void kernel_launch(void* const* d_in, const int* in_sizes, int n_in,
                              void* d_out, int out_size, void* d_ws, size_t ws_size,
                              hipStream_t stream) {
    const float* x      = (const float*)d_in[0];
    const float* S0     = (const float*)d_in[1];
    const float* W_in   = (const float*)d_in[2];
    const float* W_k    = (const float*)d_in[3];
    const float* W_v    = (const float*)d_in[4];
    const float* W_q    = (const float*)d_in[5];
    const float* W_beta = (const float*)d_in[6];
    const float* b_beta = (const float*)d_in[7];

    float* ws   = (float*)d_ws;
    float* out_ = (float*)d_out;                  // [T,B,512]
    float* Sfin = out_ + (size_t)TT * BB * HN;    // [B,H,N,N]

    const size_t NEED_PRE = (size_t)(33554432 + 16777216 + 2*2097152) * 4; // 226.5 MB
    const bool pre = (ws_size >= NEED_PRE);

    if (pre) {
        float* proj   = ws;                         // 33554432 floats (packet layout)
        char*  xsplit = (char*)(ws + 33554432);     // 67108864 bytes
        float* Weff   = ws + 33554432 + 16777216;   // 2097152 floats
        char*  wsplit = (char*)(Weff + 2097152);    // 8 MB

        hipError_t aerr = hipFuncSetAttribute(
            reinterpret_cast<const void*>(&gemm_mfma8),
            hipFuncAttributeMaxDynamicSharedMemorySize, 131072);

        gemm_f32c<<<dim3(16, 32), dim3(256), 0, stream>>>(W_k, W_v, W_q, W_beta, W_in, Weff);
        wconv<<<dim3(512), dim3(256), 0, stream>>>(Weff, wsplit);   // weights -> split
        wconv<<<dim3(4096), dim3(256), 0, stream>>>(x, xsplit);     // x -> split
        if (aerr == hipSuccess) {
            gemm_mfma8<<<dim3(512), dim3(512), 131072, stream>>>(xsplit, wsplit, proj, b_beta);
        } else {
            gemm_mfma<true><<<dim3(2048), dim3(256), 0, stream>>>(x, xsplit, wsplit, proj, b_beta);
        }
        recur<<<dim3(256), dim3(256), 0, stream>>>(proj, S0, out_, Sfin);
    } else {
        float* proj   = ws;
        float* Weff   = ws + 33554432;
        char*  wsplit = (char*)(Weff + 2097152);

        gemm_f32c<<<dim3(16, 32), dim3(256), 0, stream>>>(W_k, W_v, W_q, W_beta, W_in, Weff);
        wconv<<<dim3(512), dim3(256), 0, stream>>>(Weff, wsplit);
        gemm_mfma<false><<<dim3(2048), dim3(256), 0, stream>>>(x, nullptr, wsplit, proj, b_beta);
        recur<<<dim3(256), dim3(256), 0, stream>>>(proj, S0, out_, Sfin);
    }
}

// Round 16
// 481.759 us; speedup vs baseline: 1.2289x; 1.2289x over previous
//
#include <hip/hip_runtime.h>
#include <hip/hip_bf16.h>
#include <stdint.h>

#define TT 2048
#define BB 8
#define DD 1024
#define FF 2048   // 4*H*N
#define HN 512
#define KB_CNT 32         // DD/32 k-blocks
#define ROWB 128          // bytes per (row, k-block) in SPLIT layout (A)
#define MSTRIDE 4096      // bytes per row, split layout = KB_CNT*ROWB
#define BROWB 64          // bytes per (row, k-block) in SINGLE-fp16 layout (B)
#define BSTRIDE 2048      // bytes per row, single layout = KB_CNT*BROWB
#define PF 8              // recurrence pipeline depth (R9-proven floor)

typedef float f32x4 __attribute__((ext_vector_type(4)));
typedef float f32x2 __attribute__((ext_vector_type(2)));
typedef _Float16 h8_t __attribute__((ext_vector_type(8)));

#define CC   2.88539008f    // 2/ln2
#define SQC  1.69864360f    // sqrt(2/ln2)

// ---------- fast math helpers ----------
__device__ __forceinline__ float fexp2(float x){ return __builtin_amdgcn_exp2f(x); }
__device__ __forceinline__ float frcp(float x){ return __builtin_amdgcn_rcpf(x); }
__device__ __forceinline__ float fsqrt_(float x){ return __builtin_amdgcn_sqrtf(x); }
__device__ __forceinline__ float fast_sigmoid(float x){
    return frcp(1.0f + fexp2(-1.44269504f * x));
}

// DPP butterfly add
template<int CTRL>
__device__ __forceinline__ float dppadd(float v){
    int x = __builtin_amdgcn_update_dpp(0, __float_as_int(v), CTRL, 0xf, 0xf, true);
    return v + __int_as_float(x);
}
__device__ __forceinline__ float reduce16(float v){
    v = dppadd<0xB1>(v);   // + lane^1
    v = dppadd<0x4E>(v);   // + lane^2
    v = dppadd<0x141>(v);  // row_half_mirror: + lane^4
    v = dppadd<0x140>(v);  // row_mirror:      + lane^8
    return v;
}

// ---------- split fp32 -> (hi,lo) fp16 ----------
__device__ __forceinline__ void split8(const float* f, int4& hi, int4& lo){
    union { _Float16 h[8]; int4 i; } a, c;
    #pragma unroll
    for (int u = 0; u < 8; ++u) {
        _Float16 h = (_Float16)f[u];
        a.h[u] = h;
        c.h[u] = (_Float16)(f[u] - (float)h);
    }
    hi = a.i; lo = c.i;
}
// ---------- fp32 -> single fp16 (8 at a time) ----------
__device__ __forceinline__ int4 cvt8(const float* f){
    union { _Float16 h[8]; int4 i; } a;
    #pragma unroll
    for (int u = 0; u < 8; ++u) a.h[u] = (_Float16)f[u];
    return a.i;
}

// ---------- Weff = [Wk;Wv;Wq;Wb] * W_in, fused concat, 64x64 tiles ----------
__global__ __launch_bounds__(256)
void gemm_f32c(const float* __restrict__ s0, const float* __restrict__ s1,
               const float* __restrict__ s2, const float* __restrict__ s3,
               const float* __restrict__ B, float* __restrict__ C)
{
    __shared__ __align__(16) float As[16][68];
    __shared__ __align__(16) float Bs[16][72];
    const int tid = threadIdx.x;
    const int tx = tid & 15, ty = tid >> 4;
    const int n0 = blockIdx.x * 64, m0 = blockIdx.y * 64;
    float acc[4][4] = {};

    const int arow = tid >> 2, ac4 = (tid & 3) << 2;
    const int f = m0 + arow;
    const float* asrc = ((f < 512) ? s0 : (f < 1024) ? s1 : (f < 1536) ? s2 : s3)
                        + (size_t)(f & 511) * DD + ac4;
    const int bk = tid >> 4, bc = tid & 15;

    for (int k0 = 0; k0 < DD; k0 += 16) {
        float4 av = *(const float4*)(asrc + k0);
        As[ac4+0][arow] = av.x; As[ac4+1][arow] = av.y;
        As[ac4+2][arow] = av.z; As[ac4+3][arow] = av.w;
        float4 bv = *(const float4*)&B[(size_t)(k0 + bk) * DD + n0 + bc * 4];
        int p = bc + (bc >> 3);
        *(float4*)&Bs[bk][p << 2] = bv;
        __syncthreads();
        #pragma unroll
        for (int kk = 0; kk < 16; ++kk) {
            float a[4], b[4];
            *(float4*)&a[0] = *(const float4*)&As[kk][ty * 4];
            int p2 = tx + (tx >> 3);
            *(float4*)&b[0] = *(const float4*)&Bs[kk][p2 << 2];
            #pragma unroll
            for (int i = 0; i < 4; ++i)
                #pragma unroll
                for (int j = 0; j < 4; ++j)
                    acc[i][j] = __builtin_fmaf(a[i], b[j], acc[i][j]);
        }
        __syncthreads();
    }
    #pragma unroll
    for (int ii = 0; ii < 4; ++ii) {
        float4 v;
        v.x = acc[ii][0]; v.y = acc[ii][1]; v.z = acc[ii][2]; v.w = acc[ii][3];
        *(float4*)&C[(size_t)(m0 + ty * 4 + ii) * DD + n0 + tx * 4] = v;
    }
}

// ---------- x: fp32 -> SPLIT fp16 pre-swizzled (A operand) ----------
__global__ __launch_bounds__(256)
void wconv(const float* __restrict__ W, char* __restrict__ out)
{
    int gid = blockIdx.x * 256 + threadIdx.x;
    int n  = gid >> 6;
    int kh = gid & 63;
    const float* src = W + (size_t)n * DD + kh * 16;
    float f[16];
    *(float4*)&f[0]  = *(const float4*)(src + 0);
    *(float4*)&f[4]  = *(const float4*)(src + 4);
    *(float4*)&f[8]  = *(const float4*)(src + 8);
    *(float4*)&f[12] = *(const float4*)(src + 12);
    int4 hi0, hi1, lo0, lo1;
    split8(&f[0], hi0, lo0);
    split8(&f[8], hi1, lo1);
    int kb = kh >> 1, c0 = (kh & 1) * 2, rs = n & 7;
    char* dst = out + (size_t)n * MSTRIDE + kb * ROWB;
    *(int4*)(dst + (((c0+0) ^ rs) * 16)) = hi0;
    *(int4*)(dst + (((c0+1) ^ rs) * 16)) = hi1;
    *(int4*)(dst + (((c0+4) ^ rs) * 16)) = lo0;
    *(int4*)(dst + (((c0+5) ^ rs) * 16)) = lo1;
}

// ---------- Weff: fp32 -> SINGLE fp16 pre-swizzled (B operand) ----------
// layout: [row][kb][slot 0..3][16B], chunk c (8 fp16) at slot c ^ (row&3).
__global__ __launch_bounds__(256)
void wconv2(const float* __restrict__ W, char* __restrict__ out)
{
    int gid = blockIdx.x * 256 + threadIdx.x;   // 512 blocks -> 2048 rows x 64
    int n  = gid >> 6;
    int kh = gid & 63;          // 16 floats per thread
    const float* src = W + (size_t)n * DD + kh * 16;
    float f[16];
    *(float4*)&f[0]  = *(const float4*)(src + 0);
    *(float4*)&f[4]  = *(const float4*)(src + 4);
    *(float4*)&f[8]  = *(const float4*)(src + 8);
    *(float4*)&f[12] = *(const float4*)(src + 12);
    int4 h0 = cvt8(&f[0]);
    int4 h1 = cvt8(&f[8]);
    int kb = kh >> 1, c0 = (kh & 1) * 2, rs = n & 3;
    char* dst = out + (size_t)n * BSTRIDE + kb * BROWB;
    *(int4*)(dst + (((c0+0) ^ rs) * 16)) = h0;
    *(int4*)(dst + (((c0+1) ^ rs) * 16)) = h1;
}

// Epilogue packet layout (8192B per row m, 512B per h), de-interleaved:
//   k@0 + idx*4, q@128 + idx*4, v~@256 + idx*4 (SQC*v), b~@384 + idx*4
#define EPI_STORE(Cb, rbase, reg, hh, idx, blk, v, bb) { \
    char* rowp = (char*)(Cb) + (size_t)((rbase) + (reg)) * 8192 + (hh) * 512; \
    int sub_ = ((blk) == 0) ? 0 : ((blk) == 2) ? 1 : ((blk) == 1) ? 2 : 3; \
    float v_ = (v); \
    if ((blk) == 1) v_ = SQC * v_; \
    else if ((blk) == 3) v_ = CC * fast_sigmoid(v_ + (bb)); \
    *(float*)(rowp + sub_ * 128 + (idx) * 4) = v_; \
}

// ---------- 256x256 dbuf MFMA GEMM: A split fp16, B single fp16, 2-pass ----------
// LDS per buffer: A 32KB + B 16KB = 48KB; 2 buffers = 96KB dynamic.
// Per tile: {vmcnt(0); barrier} then all 6 staging instrs (4 A + 2 B) for
// t+1, then 2-pass MFMA (Ah*B then Al*B), 64 MFMA/wave/tile.
__global__ __launch_bounds__(512, 1)
void gemm_mfma8(const char* __restrict__ Axp, const char* __restrict__ Wsp,
                float* __restrict__ C, const float* __restrict__ bias)
{
    extern __shared__ char ldsb[];   // 98304
    const int tid  = threadIdx.x;
    const int wave = tid >> 6, lane = tid & 63;
    const int wm = wave >> 2, wn = wave & 3;        // 2 x 4 waves
    const int nt = blockIdx.x & 7, mt = blockIdx.x >> 3;
    const int m0 = mt * 256, n0 = nt * 256;

    f32x4 acc[8][4] = {};

    // A staging (split): wave stages rows [wave*32,+32): 4 instrs x 1KB
    const char* aT = Axp + (size_t)(m0 + wave * 32 + (lane >> 3)) * MSTRIDE + (lane & 7) * 16;
    // B staging (single): wave stages rows [wave*32,+32): 2 instrs x 1KB
    const char* bT = Wsp + (size_t)(n0 + wave * 32 + (lane >> 2)) * BSTRIDE + (lane & 3) * 16;
    const int ldstA = wave * 32 * 128;   // A LDS base for this wave
    const int ldstB = wave * 32 * 64;    // B LDS base (within B region)

    const int fl = lane & 15, fh = lane >> 4;
    const int shiA = (fh ^ (fl & 7)) * 16;
    const int sloA = ((fh + 4) ^ (fl & 7)) * 16;
    const int shiB = (fh ^ (fl & 3)) * 16;

    // prologue: stage tile 0 into buf 0
    {
        char* L = ldsb;
        #pragma unroll
        for (int g = 0; g < 4; ++g)
            __builtin_amdgcn_global_load_lds(
                (const __attribute__((address_space(1))) uint32_t*)(aT + (size_t)g * 8 * MSTRIDE),
                (__attribute__((address_space(3))) uint32_t*)(L + ldstA + g * 1024),
                16, 0, 0);
        #pragma unroll
        for (int g = 0; g < 2; ++g)
            __builtin_amdgcn_global_load_lds(
                (const __attribute__((address_space(1))) uint32_t*)(bT + (size_t)g * 16 * BSTRIDE),
                (__attribute__((address_space(3))) uint32_t*)(L + 32768 + ldstB + g * 1024),
                16, 0, 0);
    }

    union u8 { int4 i; h8_t h; };
    u8 Ah[4], Al[4], Bf[4];

    for (int t = 0; t < KB_CNT; ++t) {
        char* Lc = ldsb + (t & 1) * 49152;
        char* Ln = ldsb + ((t + 1) & 1) * 49152;
        const bool stg = (t + 1 < KB_CNT);
        const char* aN = aT + ROWB;
        const char* bN = bT + BROWB;

        asm volatile("s_waitcnt vmcnt(0)" ::: "memory");
        __builtin_amdgcn_s_barrier();
        asm volatile("" ::: "memory");

        if (stg) {
            #pragma unroll
            for (int g = 0; g < 4; ++g)
                __builtin_amdgcn_global_load_lds(
                    (const __attribute__((address_space(1))) uint32_t*)(aN + (size_t)g * 8 * MSTRIDE),
                    (__attribute__((address_space(3))) uint32_t*)(Ln + ldstA + g * 1024),
                    16, 0, 0);
            #pragma unroll
            for (int g = 0; g < 2; ++g)
                __builtin_amdgcn_global_load_lds(
                    (const __attribute__((address_space(1))) uint32_t*)(bN + (size_t)g * 16 * BSTRIDE),
                    (__attribute__((address_space(3))) uint32_t*)(Ln + 32768 + ldstB + g * 1024),
                    16, 0, 0);
        }

        // ---- B fragments (loaded once, reused both halves) ----
        #pragma unroll
        for (int f = 0; f < 4; ++f) {
            const char* base = Lc + 32768 + (wn * 64 + f * 16 + fl) * 64;
            Bf[f].i = *(const int4*)(base + shiB);
        }

        // ---- half 1: fm 0-3 ----
        #pragma unroll
        for (int f = 0; f < 4; ++f) {
            const char* base = Lc + (wm * 128 + f * 16 + fl) * 128;
            Ah[f].i = *(const int4*)(base + shiA);
            Al[f].i = *(const int4*)(base + sloA);
        }
        __builtin_amdgcn_s_setprio(1);
        #pragma unroll
        for (int i = 0; i < 4; ++i)
            #pragma unroll
            for (int j = 0; j < 4; ++j)
                acc[i][j] = __builtin_amdgcn_mfma_f32_16x16x32_f16(Ah[i].h, Bf[j].h, acc[i][j], 0, 0, 0);
        #pragma unroll
        for (int i = 0; i < 4; ++i)
            #pragma unroll
            for (int j = 0; j < 4; ++j)
                acc[i][j] = __builtin_amdgcn_mfma_f32_16x16x32_f16(Al[i].h, Bf[j].h, acc[i][j], 0, 0, 0);
        __builtin_amdgcn_s_setprio(0);

        // ---- half 2: fm 4-7 ----
        #pragma unroll
        for (int f = 0; f < 4; ++f) {
            const char* base = Lc + (wm * 128 + (f + 4) * 16 + fl) * 128;
            Ah[f].i = *(const int4*)(base + shiA);
            Al[f].i = *(const int4*)(base + sloA);
        }
        __builtin_amdgcn_s_setprio(1);
        #pragma unroll
        for (int i = 0; i < 4; ++i)
            #pragma unroll
            for (int j = 0; j < 4; ++j)
                acc[i + 4][j] = __builtin_amdgcn_mfma_f32_16x16x32_f16(Ah[i].h, Bf[j].h, acc[i + 4][j], 0, 0, 0);
        #pragma unroll
        for (int i = 0; i < 4; ++i)
            #pragma unroll
            for (int j = 0; j < 4; ++j)
                acc[i + 4][j] = __builtin_amdgcn_mfma_f32_16x16x32_f16(Al[i].h, Bf[j].h, acc[i + 4][j], 0, 0, 0);
        __builtin_amdgcn_s_setprio(0);

        aT += ROWB; bT += BROWB;
    }

    const int blk = nt >> 1;   // 0:k 1:v 2:q 3:beta
    if (blk == 0) {
        #pragma unroll
        for (int fm = 0; fm < 8; ++fm)
            #pragma unroll
            for (int hg = 0; hg < 2; ++hg)
                #pragma unroll
                for (int reg = 0; reg < 4; ++reg) {
                    float a = acc[fm][hg*2][reg], c = acc[fm][hg*2+1][reg];
                    float p = __builtin_fmaf(a, a, c * c);
                    p = reduce16(p);
                    float rn = SQC * frcp(fsqrt_(p) + 1e-6f);
                    acc[fm][hg*2][reg]   = a * rn;
                    acc[fm][hg*2+1][reg] = c * rn;
                }
    }

    #pragma unroll
    for (int fm = 0; fm < 8; ++fm) {
        int rbase = m0 + wm * 128 + fm * 16 + fh * 4;
        #pragma unroll
        for (int fn = 0; fn < 4; ++fn) {
            int col = n0 + wn * 64 + fn * 16 + fl;
            int hh  = (col >> 5) & 15;
            int idx = col & 31;
            float bb = (blk == 3) ? bias[col - 3 * HN] : 0.0f;
            #pragma unroll
            for (int reg = 0; reg < 4; ++reg) {
                float v = acc[fm][fn][reg];
                EPI_STORE(C, rbase, reg, hh, idx, blk, v, bb);
            }
        }
    }
}

// ---------- legacy 128x128 MFMA GEMM (fallback; B single fp16) ----------
__global__ __launch_bounds__(256)
void gemm_mfma(const float* __restrict__ A, const char* __restrict__ Wsp,
               float* __restrict__ C, const float* __restrict__ bias)
{
    __shared__ char lds[24576];
    char* Asb = lds;            // 16KB split A
    char* Bsb = lds + 16384;    // 8KB single B

    const int tid  = threadIdx.x;
    const int wave = tid >> 6, lane = tid & 63;
    const int wm = wave >> 1, wn = wave & 1;
    const int nt = blockIdx.x & 15, mt = blockIdx.x >> 4;
    const int m0 = mt * 128, n0 = nt * 128;

    f32x4 acc[4][4] = {};

    const int ar = tid >> 1, akh = tid & 1, ars = ar & 7, ac0 = akh * 2;
    const float* asrc = A + (size_t)(m0 + ar) * DD + akh * 16;
    char* awr = Asb + ar * ROWB;

    const char* bsrc_base = Wsp + (size_t)n0 * BSTRIDE;

    const int fl = lane & 15, fh = lane >> 4;
    const int shiA = (fh ^ (fl & 7)) * 16;
    const int sloA = ((fh + 4) ^ (fl & 7)) * 16;
    const int shiB = (fh ^ (fl & 3)) * 16;

    for (int ks = 0; ks < KB_CNT; ++ks) {
        #pragma unroll
        for (int gg = 0; gg < 2; ++gg) {
            int g = wave * 2 + gg;
            const char* src = bsrc_base + (size_t)(g * 16 + (lane >> 2)) * BSTRIDE
                              + ks * BROWB + (lane & 3) * 16;
            __builtin_amdgcn_global_load_lds(
                (const __attribute__((address_space(1))) uint32_t*)src,
                (__attribute__((address_space(3))) uint32_t*)(Bsb + g * 1024),
                16, 0, 0);
        }
        {
            const float* ap = asrc + ks * 32;
            float f[16];
            *(float4*)&f[0]  = *(const float4*)(ap + 0);
            *(float4*)&f[4]  = *(const float4*)(ap + 4);
            *(float4*)&f[8]  = *(const float4*)(ap + 8);
            *(float4*)&f[12] = *(const float4*)(ap + 12);
            int4 hi0, hi1, lo0, lo1;
            split8(&f[0], hi0, lo0);
            split8(&f[8], hi1, lo1);
            *(int4*)(awr + (((ac0+0) ^ ars) * 16)) = hi0;
            *(int4*)(awr + (((ac0+1) ^ ars) * 16)) = hi1;
            *(int4*)(awr + (((ac0+4) ^ ars) * 16)) = lo0;
            *(int4*)(awr + (((ac0+5) ^ ars) * 16)) = lo1;
        }
        __syncthreads();

        union { int4 i; h8_t h; } ah[4], al[4], bf[4];
        #pragma unroll
        for (int fm = 0; fm < 4; ++fm) {
            const char* base = Asb + (wm * 64 + fm * 16 + fl) * ROWB;
            ah[fm].i = *(const int4*)(base + shiA);
            al[fm].i = *(const int4*)(base + sloA);
        }
        #pragma unroll
        for (int fn = 0; fn < 4; ++fn) {
            const char* base = Bsb + (wn * 64 + fn * 16 + fl) * BROWB;
            bf[fn].i = *(const int4*)(base + shiB);
        }
        #pragma unroll
        for (int fm = 0; fm < 4; ++fm)
            #pragma unroll
            for (int fn = 0; fn < 4; ++fn) {
                acc[fm][fn] = __builtin_amdgcn_mfma_f32_16x16x32_f16(ah[fm].h, bf[fn].h, acc[fm][fn], 0, 0, 0);
                acc[fm][fn] = __builtin_amdgcn_mfma_f32_16x16x32_f16(al[fm].h, bf[fn].h, acc[fm][fn], 0, 0, 0);
            }
        __syncthreads();
    }

    const int blk = nt >> 2;   // 0:k 1:v 2:q 3:beta
    if (blk == 0) {
        #pragma unroll
        for (int fm = 0; fm < 4; ++fm)
            #pragma unroll
            for (int hg = 0; hg < 2; ++hg)
                #pragma unroll
                for (int reg = 0; reg < 4; ++reg) {
                    float a = acc[fm][hg*2][reg], c = acc[fm][hg*2+1][reg];
                    float p = __builtin_fmaf(a, a, c * c);
                    p = reduce16(p);
                    float rn = SQC * frcp(fsqrt_(p) + 1e-6f);
                    acc[fm][hg*2][reg]   = a * rn;
                    acc[fm][hg*2+1][reg] = c * rn;
                }
    }

    #pragma unroll
    for (int fm = 0; fm < 4; ++fm) {
        int rbase = m0 + wm * 64 + fm * 16 + fh * 4;
        #pragma unroll
        for (int fn = 0; fn < 4; ++fn) {
            int col = n0 + wn * 64 + fn * 16 + fl;
            int hh  = (col >> 5) & 15;
            int idx = col & 31;
            float bb = (blk == 3) ? bias[col - 3 * HN] : 0.0f;
            #pragma unroll
            for (int reg = 0; reg < 4; ++reg) {
                float v = acc[fm][fn][reg];
                EPI_STORE(C, rbase, reg, hh, idx, blk, v, bb);
            }
        }
    }
}

// ---------- sequential recurrence (R9-proven 248us floor; do not touch) ----------
__global__ __launch_bounds__(256)
void recur(const float* __restrict__ proj, const float* __restrict__ S0,
           float* __restrict__ out, float* __restrict__ Sfin)
{
    const int tid = threadIdx.x;
    const int bx  = blockIdx.x;
    const int bh  = bx >> 1;                       // chain 0..127
    const int b   = bh >> 4, h = bh & 15;
    const int i   = ((bx & 1) << 4) + (tid >> 4);  // state row 0..31
    const int jl  = tid & 15;                      // owns j = 2jl, 2jl+1

    f32x2 S;
    {
        const float* s0p = S0 + (size_t)bh * 1024 + i * 32 + 2 * jl;
        S[0] = s0p[0]; S[1] = s0p[1];
    }

    const char* pkq = (const char*)proj + (size_t)b * 8192 + h * 512 + jl * 8;
    const char* pvb = (const char*)proj + (size_t)b * 8192 + h * 512 + 256 + i * 4;
    const size_t rstep = (size_t)BB * 8192;        // 65536 B per t

    f32x2 K2[PF], Q2[PF];
    float V[PF], Bt[PF];

    #pragma unroll
    for (int p = 0; p < PF; ++p) {
        asm volatile("global_load_dwordx2 %0, %1, off"            : "=v"(K2[p]) : "v"(pkq));
        asm volatile("global_load_dwordx2 %0, %1, off offset:128" : "=v"(Q2[p]) : "v"(pkq));
        asm volatile("global_load_dword %0, %1, off"              : "=v"(V[p])  : "v"(pvb));
        asm volatile("global_load_dword %0, %1, off offset:128"   : "=v"(Bt[p]) : "v"(pvb));
        pkq += rstep; pvb += rstep;
    }

    asm volatile("s_waitcnt vmcnt(28)" : "+v"(V[0]), "+v"(Bt[0]));
    float cv = V[0];
    f32x2 bS = Bt[0] * S;

    float* pout = out + (size_t)b * HN + h * 32 + i;   // stored when jl==0

    for (int t0 = 0; t0 < TT; t0 += PF) {
        float osave[PF];
        #pragma unroll
        for (int p = 0; p < PF; ++p) {
            const int pn = (p + 1) & (PF - 1);
            asm volatile("s_waitcnt vmcnt(24)"
                : "+v"(K2[p]), "+v"(Q2[p]), "+v"(V[pn]), "+v"(Bt[pn]));

            f32x2 k2 = K2[p];
            float rr = __builtin_fmaf(S[1], k2[1], S[0] * k2[0]);
            rr = reduce16(rr);
            float d = cv - rr;
            f32x2 a = d * k2 + bS;
            f32x2 e; e[0] = fexp2(a[0]); e[1] = fexp2(a[1]);
            f32x2 e1 = e + 1.0f;
            f32x2 r; r[0] = frcp(e1[0]); r[1] = frcp(e1[1]);
            S = -2.0f * r + 1.0f;

            f32x2 q2 = Q2[p];
            osave[p] = __builtin_fmaf(S[1], q2[1], S[0] * q2[0]);

            cv = V[pn];
            bS = Bt[pn] * S;

            asm volatile("global_load_dwordx2 %0, %1, off"            : "=v"(K2[p]) : "v"(pkq));
            asm volatile("global_load_dwordx2 %0, %1, off offset:128" : "=v"(Q2[p]) : "v"(pkq));
            asm volatile("global_load_dword %0, %1, off"              : "=v"(V[p])  : "v"(pvb));
            asm volatile("global_load_dword %0, %1, off offset:128"   : "=v"(Bt[p]) : "v"(pvb));
            pkq += rstep; pvb += rstep;
        }
        #pragma unroll
        for (int p = 0; p < PF; ++p) osave[p] = reduce16(osave[p]);
        if (jl == 0) {
            #pragma unroll
            for (int p = 0; p < PF; ++p) {
                float sq = osave[p];
                float sg = fast_sigmoid(sq);
                pout[(size_t)p * (BB * HN)] = sq * sq * sg;
            }
        }
        pout += (size_t)PF * (BB * HN);
    }

    {
        float* sf = Sfin + (size_t)bh * 1024 + i * 32 + 2 * jl;
        sf[0] = S[0]; sf[1] = S[1];
    }
}

extern "C" void kernel_launch(void* const* d_in, const int* in_sizes, int n_in,
                              void* d_out, int out_size, void* d_ws, size_t ws_size,
                              hipStream_t stream) {
    const float* x      = (const float*)d_in[0];
    const float* S0     = (const float*)d_in[1];
    const float* W_in   = (const float*)d_in[2];
    const float* W_k    = (const float*)d_in[3];
    const float* W_v    = (const float*)d_in[4];
    const float* W_q    = (const float*)d_in[5];
    const float* W_beta = (const float*)d_in[6];
    const float* b_beta = (const float*)d_in[7];

    float* ws   = (float*)d_ws;
    float* out_ = (float*)d_out;                  // [T,B,512]
    float* Sfin = out_ + (size_t)TT * BB * HN;    // [B,H,N,N]

    const size_t NEED_PRE = (size_t)(33554432 + 16777216 + 2*2097152) * 4; // 226.5 MB
    const bool pre = (ws_size >= NEED_PRE);

    if (pre) {
        float* proj   = ws;                         // 134 MB (packet layout)
        char*  xsplit = (char*)(ws + 33554432);     // 67 MB (A split)
        float* Weff   = ws + 33554432 + 16777216;   // 8 MB
        char*  wsplit = (char*)(Weff + 2097152);    // 4 MB (B single fp16)

        hipError_t aerr = hipFuncSetAttribute(
            reinterpret_cast<const void*>(&gemm_mfma8),
            hipFuncAttributeMaxDynamicSharedMemorySize, 98304);

        gemm_f32c<<<dim3(16, 32), dim3(256), 0, stream>>>(W_k, W_v, W_q, W_beta, W_in, Weff);
        wconv2<<<dim3(512), dim3(256), 0, stream>>>(Weff, wsplit);  // weights -> single fp16
        wconv<<<dim3(4096), dim3(256), 0, stream>>>(x, xsplit);     // x -> split fp16
        if (aerr == hipSuccess) {
            gemm_mfma8<<<dim3(512), dim3(512), 98304, stream>>>(xsplit, wsplit, proj, b_beta);
        } else {
            gemm_mfma<<<dim3(2048), dim3(256), 0, stream>>>(x, wsplit, proj, b_beta);
        }
        recur<<<dim3(256), dim3(256), 0, stream>>>(proj, S0, out_, Sfin);
    } else {
        float* proj   = ws;
        float* Weff   = ws + 33554432;
        char*  wsplit = (char*)(Weff + 2097152);

        gemm_f32c<<<dim3(16, 32), dim3(256), 0, stream>>>(W_k, W_v, W_q, W_beta, W_in, Weff);
        wconv2<<<dim3(512), dim3(256), 0, stream>>>(Weff, wsplit);
        gemm_mfma<<<dim3(2048), dim3(256), 0, stream>>>(x, wsplit, proj, b_beta);
        recur<<<dim3(256), dim3(256), 0, stream>>>(proj, S0, out_, Sfin);
    }
}

// Round 17
// 430.262 us; speedup vs baseline: 1.3760x; 1.1197x over previous
//
#include <hip/hip_runtime.h>
#include <hip/hip_bf16.h>
#include <stdint.h>

#define TT 2048
#define BB 8
#define DD 1024
#define FF 2048   // 4*H*N
#define HN 512
#define KB_CNT 32         // DD/32 k-blocks
#define ROWB 128          // bytes per (row, k-block) in SPLIT layout (legacy A)
#define MSTRIDE 4096      // bytes per row, split layout
#define BROWB 64          // bytes per (row, k-block) in SINGLE-fp16 layout
#define BSTRIDE 2048      // bytes per row, single layout = KB_CNT*BROWB
#define PF 8              // recurrence pipeline depth (R9-proven floor)

typedef float f32x4 __attribute__((ext_vector_type(4)));
typedef float f32x2 __attribute__((ext_vector_type(2)));
typedef _Float16 h8_t __attribute__((ext_vector_type(8)));

#define CC   2.88539008f    // 2/ln2
#define SQC  1.69864360f    // sqrt(2/ln2)

// ---------- fast math helpers ----------
__device__ __forceinline__ float fexp2(float x){ return __builtin_amdgcn_exp2f(x); }
__device__ __forceinline__ float frcp(float x){ return __builtin_amdgcn_rcpf(x); }
__device__ __forceinline__ float fsqrt_(float x){ return __builtin_amdgcn_sqrtf(x); }
__device__ __forceinline__ float fast_sigmoid(float x){
    return frcp(1.0f + fexp2(-1.44269504f * x));
}

// DPP butterfly add
template<int CTRL>
__device__ __forceinline__ float dppadd(float v){
    int x = __builtin_amdgcn_update_dpp(0, __float_as_int(v), CTRL, 0xf, 0xf, true);
    return v + __int_as_float(x);
}
__device__ __forceinline__ float reduce16(float v){
    v = dppadd<0xB1>(v);   // + lane^1
    v = dppadd<0x4E>(v);   // + lane^2
    v = dppadd<0x141>(v);  // row_half_mirror: + lane^4
    v = dppadd<0x140>(v);  // row_mirror:      + lane^8
    return v;
}

// ---------- split fp32 -> (hi,lo) fp16 (legacy fallback) ----------
__device__ __forceinline__ void split8(const float* f, int4& hi, int4& lo){
    union { _Float16 h[8]; int4 i; } a, c;
    #pragma unroll
    for (int u = 0; u < 8; ++u) {
        _Float16 h = (_Float16)f[u];
        a.h[u] = h;
        c.h[u] = (_Float16)(f[u] - (float)h);
    }
    hi = a.i; lo = c.i;
}
// ---------- fp32 -> single fp16 (8 at a time) ----------
__device__ __forceinline__ int4 cvt8(const float* f){
    union { _Float16 h[8]; int4 i; } a;
    #pragma unroll
    for (int u = 0; u < 8; ++u) a.h[u] = (_Float16)f[u];
    return a.i;
}

// ---------- Weff = [Wk;Wv;Wq;Wb] * W_in, fused concat, 64x64 tiles ----------
__global__ __launch_bounds__(256)
void gemm_f32c(const float* __restrict__ s0, const float* __restrict__ s1,
               const float* __restrict__ s2, const float* __restrict__ s3,
               const float* __restrict__ B, float* __restrict__ C)
{
    __shared__ __align__(16) float As[16][68];
    __shared__ __align__(16) float Bs[16][72];
    const int tid = threadIdx.x;
    const int tx = tid & 15, ty = tid >> 4;
    const int n0 = blockIdx.x * 64, m0 = blockIdx.y * 64;
    float acc[4][4] = {};

    const int arow = tid >> 2, ac4 = (tid & 3) << 2;
    const int f = m0 + arow;
    const float* asrc = ((f < 512) ? s0 : (f < 1024) ? s1 : (f < 1536) ? s2 : s3)
                        + (size_t)(f & 511) * DD + ac4;
    const int bk = tid >> 4, bc = tid & 15;

    for (int k0 = 0; k0 < DD; k0 += 16) {
        float4 av = *(const float4*)(asrc + k0);
        As[ac4+0][arow] = av.x; As[ac4+1][arow] = av.y;
        As[ac4+2][arow] = av.z; As[ac4+3][arow] = av.w;
        float4 bv = *(const float4*)&B[(size_t)(k0 + bk) * DD + n0 + bc * 4];
        int p = bc + (bc >> 3);
        *(float4*)&Bs[bk][p << 2] = bv;
        __syncthreads();
        #pragma unroll
        for (int kk = 0; kk < 16; ++kk) {
            float a[4], b[4];
            *(float4*)&a[0] = *(const float4*)&As[kk][ty * 4];
            int p2 = tx + (tx >> 3);
            *(float4*)&b[0] = *(const float4*)&Bs[kk][p2 << 2];
            #pragma unroll
            for (int i = 0; i < 4; ++i)
                #pragma unroll
                for (int j = 0; j < 4; ++j)
                    acc[i][j] = __builtin_fmaf(a[i], b[j], acc[i][j]);
        }
        __syncthreads();
    }
    #pragma unroll
    for (int ii = 0; ii < 4; ++ii) {
        float4 v;
        v.x = acc[ii][0]; v.y = acc[ii][1]; v.z = acc[ii][2]; v.w = acc[ii][3];
        *(float4*)&C[(size_t)(m0 + ty * 4 + ii) * DD + n0 + tx * 4] = v;
    }
}

// ---------- fp32 -> SINGLE fp16 pre-swizzled (A and B operands) ----------
// layout: [row][kb][slot 0..3][16B], chunk c (8 fp16) at slot c ^ (row&3).
__global__ __launch_bounds__(256)
void wconv2(const float* __restrict__ W, char* __restrict__ out)
{
    int gid = blockIdx.x * 256 + threadIdx.x;
    int n  = gid >> 6;
    int kh = gid & 63;          // 16 floats per thread
    const float* src = W + (size_t)n * DD + kh * 16;
    float f[16];
    *(float4*)&f[0]  = *(const float4*)(src + 0);
    *(float4*)&f[4]  = *(const float4*)(src + 4);
    *(float4*)&f[8]  = *(const float4*)(src + 8);
    *(float4*)&f[12] = *(const float4*)(src + 12);
    int4 h0 = cvt8(&f[0]);
    int4 h1 = cvt8(&f[8]);
    int kb = kh >> 1, c0 = (kh & 1) * 2, rs = n & 3;
    char* dst = out + (size_t)n * BSTRIDE + kb * BROWB;
    *(int4*)(dst + (((c0+0) ^ rs) * 16)) = h0;
    *(int4*)(dst + (((c0+1) ^ rs) * 16)) = h1;
}

// Epilogue packet layout (8192B per row m, 512B per h), de-interleaved:
//   k@0 + idx*4, q@128 + idx*4, v~@256 + idx*4 (SQC*v), b~@384 + idx*4
#define EPI_STORE(Cb, rbase, reg, hh, idx, blk, v, bb) { \
    char* rowp = (char*)(Cb) + (size_t)((rbase) + (reg)) * 8192 + (hh) * 512; \
    int sub_ = ((blk) == 0) ? 0 : ((blk) == 2) ? 1 : ((blk) == 1) ? 2 : 3; \
    float v_ = (v); \
    if ((blk) == 1) v_ = SQC * v_; \
    else if ((blk) == 3) v_ = CC * fast_sigmoid(v_ + (bb)); \
    *(float*)(rowp + sub_ * 128 + (idx) * 4) = v_; \
}

// ---------- 256x256 dbuf MFMA GEMM: A and B single fp16 ----------
// LDS per buffer: A 16KB + B 16KB = 32KB; 2 buffers = 64KB dynamic.
// XCD-aware swizzle: xcd = bid&7 owns mt in [xcd*8, xcd*8+8); the 8 blocks
// sharing an A-panel (same mt, nt 0..7) are 8 apart in dispatch order ->
// same XCD, near-concurrent -> A L2-served 7/8 of reads. B (4MB) L2-hot.
// Per tile: {vmcnt(0); barrier}, then all 4 staging instrs for t+1,
// then 32 MFMA/wave (fm 0-7 x fn 0-3).
__global__ __launch_bounds__(512, 1)
void gemm_mfma8(const char* __restrict__ Axp, const char* __restrict__ Wsp,
                float* __restrict__ C, const float* __restrict__ bias)
{
    extern __shared__ char ldsb[];   // 65536
    const int tid  = threadIdx.x;
    const int wave = tid >> 6, lane = tid & 63;
    const int wm = wave >> 2, wn = wave & 3;        // 2 x 4 waves
    const int d  = blockIdx.x;
    const int s  = d >> 3;
    const int mt = (d & 7) * 8 + (s >> 3);          // XCD (d&7) owns 8 mt
    const int nt = s & 7;
    const int m0 = mt * 256, n0 = nt * 256;

    f32x4 acc[8][4] = {};

    // staging (single layout, both operands): wave stages rows [wave*32,+32)
    const char* aT = Axp + (size_t)(m0 + wave * 32 + (lane >> 2)) * BSTRIDE + (lane & 3) * 16;
    const char* bT = Wsp + (size_t)(n0 + wave * 32 + (lane >> 2)) * BSTRIDE + (lane & 3) * 16;
    const int ldst = wave * 32 * 64;                // 2KB per wave region

    const int fl = lane & 15, fh = lane >> 4;
    const int sslot = (fh ^ (fl & 3)) * 16;

    // prologue: stage tile 0 into buf 0 (2 A + 2 B instrs)
    {
        char* L = ldsb;
        #pragma unroll
        for (int g = 0; g < 2; ++g)
            __builtin_amdgcn_global_load_lds(
                (const __attribute__((address_space(1))) uint32_t*)(aT + (size_t)g * 16 * BSTRIDE),
                (__attribute__((address_space(3))) uint32_t*)(L + ldst + g * 1024),
                16, 0, 0);
        #pragma unroll
        for (int g = 0; g < 2; ++g)
            __builtin_amdgcn_global_load_lds(
                (const __attribute__((address_space(1))) uint32_t*)(bT + (size_t)g * 16 * BSTRIDE),
                (__attribute__((address_space(3))) uint32_t*)(L + 16384 + ldst + g * 1024),
                16, 0, 0);
    }

    union u8 { int4 i; h8_t h; };
    u8 Af[8], Bf[4];

    for (int t = 0; t < KB_CNT; ++t) {
        char* Lc = ldsb + (t & 1) * 32768;
        char* Ln = ldsb + ((t + 1) & 1) * 32768;
        const bool stg = (t + 1 < KB_CNT);
        const char* aN = aT + BROWB;
        const char* bN = bT + BROWB;

        asm volatile("s_waitcnt vmcnt(0)" ::: "memory");
        __builtin_amdgcn_s_barrier();
        asm volatile("" ::: "memory");

        if (stg) {
            #pragma unroll
            for (int g = 0; g < 2; ++g)
                __builtin_amdgcn_global_load_lds(
                    (const __attribute__((address_space(1))) uint32_t*)(aN + (size_t)g * 16 * BSTRIDE),
                    (__attribute__((address_space(3))) uint32_t*)(Ln + ldst + g * 1024),
                    16, 0, 0);
            #pragma unroll
            for (int g = 0; g < 2; ++g)
                __builtin_amdgcn_global_load_lds(
                    (const __attribute__((address_space(1))) uint32_t*)(bN + (size_t)g * 16 * BSTRIDE),
                    (__attribute__((address_space(3))) uint32_t*)(Ln + 16384 + ldst + g * 1024),
                    16, 0, 0);
        }

        // ---- fragments ----
        #pragma unroll
        for (int f = 0; f < 8; ++f) {
            const char* base = Lc + (wm * 128 + f * 16 + fl) * 64;
            Af[f].i = *(const int4*)(base + sslot);
        }
        #pragma unroll
        for (int f = 0; f < 4; ++f) {
            const char* base = Lc + 16384 + (wn * 64 + f * 16 + fl) * 64;
            Bf[f].i = *(const int4*)(base + sslot);
        }

        // ---- 32 MFMA: independent accumulators throughout ----
        __builtin_amdgcn_s_setprio(1);
        #pragma unroll
        for (int i = 0; i < 8; ++i)
            #pragma unroll
            for (int j = 0; j < 4; ++j)
                acc[i][j] = __builtin_amdgcn_mfma_f32_16x16x32_f16(Af[i].h, Bf[j].h, acc[i][j], 0, 0, 0);
        __builtin_amdgcn_s_setprio(0);

        aT += BROWB; bT += BROWB;
    }

    const int blk = nt >> 1;   // 0:k 1:v 2:q 3:beta
    if (blk == 0) {
        #pragma unroll
        for (int fm = 0; fm < 8; ++fm)
            #pragma unroll
            for (int hg = 0; hg < 2; ++hg)
                #pragma unroll
                for (int reg = 0; reg < 4; ++reg) {
                    float a = acc[fm][hg*2][reg], c = acc[fm][hg*2+1][reg];
                    float p = __builtin_fmaf(a, a, c * c);
                    p = reduce16(p);
                    float rn = SQC * frcp(fsqrt_(p) + 1e-6f);
                    acc[fm][hg*2][reg]   = a * rn;
                    acc[fm][hg*2+1][reg] = c * rn;
                }
    }

    #pragma unroll
    for (int fm = 0; fm < 8; ++fm) {
        int rbase = m0 + wm * 128 + fm * 16 + fh * 4;
        #pragma unroll
        for (int fn = 0; fn < 4; ++fn) {
            int col = n0 + wn * 64 + fn * 16 + fl;
            int hh  = (col >> 5) & 15;
            int idx = col & 31;
            float bb = (blk == 3) ? bias[col - 3 * HN] : 0.0f;
            #pragma unroll
            for (int reg = 0; reg < 4; ++reg) {
                float v = acc[fm][fn][reg];
                EPI_STORE(C, rbase, reg, hh, idx, blk, v, bb);
            }
        }
    }
}

// ---------- legacy 128x128 MFMA GEMM (fallback; A split in-kernel, B single) ----------
__global__ __launch_bounds__(256)
void gemm_mfma(const float* __restrict__ A, const char* __restrict__ Wsp,
               float* __restrict__ C, const float* __restrict__ bias)
{
    __shared__ char lds[24576];
    char* Asb = lds;            // 16KB split A
    char* Bsb = lds + 16384;    // 8KB single B

    const int tid  = threadIdx.x;
    const int wave = tid >> 6, lane = tid & 63;
    const int wm = wave >> 1, wn = wave & 1;
    const int nt = blockIdx.x & 15, mt = blockIdx.x >> 4;
    const int m0 = mt * 128, n0 = nt * 128;

    f32x4 acc[4][4] = {};

    const int ar = tid >> 1, akh = tid & 1, ars = ar & 7, ac0 = akh * 2;
    const float* asrc = A + (size_t)(m0 + ar) * DD + akh * 16;
    char* awr = Asb + ar * ROWB;

    const char* bsrc_base = Wsp + (size_t)n0 * BSTRIDE;

    const int fl = lane & 15, fh = lane >> 4;
    const int shiA = (fh ^ (fl & 7)) * 16;
    const int sloA = ((fh + 4) ^ (fl & 7)) * 16;
    const int shiB = (fh ^ (fl & 3)) * 16;

    for (int ks = 0; ks < KB_CNT; ++ks) {
        #pragma unroll
        for (int gg = 0; gg < 2; ++gg) {
            int g = wave * 2 + gg;
            const char* src = bsrc_base + (size_t)(g * 16 + (lane >> 2)) * BSTRIDE
                              + ks * BROWB + (lane & 3) * 16;
            __builtin_amdgcn_global_load_lds(
                (const __attribute__((address_space(1))) uint32_t*)src,
                (__attribute__((address_space(3))) uint32_t*)(Bsb + g * 1024),
                16, 0, 0);
        }
        {
            const float* ap = asrc + ks * 32;
            float f[16];
            *(float4*)&f[0]  = *(const float4*)(ap + 0);
            *(float4*)&f[4]  = *(const float4*)(ap + 4);
            *(float4*)&f[8]  = *(const float4*)(ap + 8);
            *(float4*)&f[12] = *(const float4*)(ap + 12);
            int4 hi0, hi1, lo0, lo1;
            split8(&f[0], hi0, lo0);
            split8(&f[8], hi1, lo1);
            *(int4*)(awr + (((ac0+0) ^ ars) * 16)) = hi0;
            *(int4*)(awr + (((ac0+1) ^ ars) * 16)) = hi1;
            *(int4*)(awr + (((ac0+4) ^ ars) * 16)) = lo0;
            *(int4*)(awr + (((ac0+5) ^ ars) * 16)) = lo1;
        }
        __syncthreads();

        union { int4 i; h8_t h; } ah[4], al[4], bf[4];
        #pragma unroll
        for (int fm = 0; fm < 4; ++fm) {
            const char* base = Asb + (wm * 64 + fm * 16 + fl) * ROWB;
            ah[fm].i = *(const int4*)(base + shiA);
            al[fm].i = *(const int4*)(base + sloA);
        }
        #pragma unroll
        for (int fn = 0; fn < 4; ++fn) {
            const char* base = Bsb + (wn * 64 + fn * 16 + fl) * BROWB;
            bf[fn].i = *(const int4*)(base + shiB);
        }
        #pragma unroll
        for (int fm = 0; fm < 4; ++fm)
            #pragma unroll
            for (int fn = 0; fn < 4; ++fn) {
                acc[fm][fn] = __builtin_amdgcn_mfma_f32_16x16x32_f16(ah[fm].h, bf[fn].h, acc[fm][fn], 0, 0, 0);
                acc[fm][fn] = __builtin_amdgcn_mfma_f32_16x16x32_f16(al[fm].h, bf[fn].h, acc[fm][fn], 0, 0, 0);
            }
        __syncthreads();
    }

    const int blk = nt >> 2;   // 0:k 1:v 2:q 3:beta
    if (blk == 0) {
        #pragma unroll
        for (int fm = 0; fm < 4; ++fm)
            #pragma unroll
            for (int hg = 0; hg < 2; ++hg)
                #pragma unroll
                for (int reg = 0; reg < 4; ++reg) {
                    float a = acc[fm][hg*2][reg], c = acc[fm][hg*2+1][reg];
                    float p = __builtin_fmaf(a, a, c * c);
                    p = reduce16(p);
                    float rn = SQC * frcp(fsqrt_(p) + 1e-6f);
                    acc[fm][hg*2][reg]   = a * rn;
                    acc[fm][hg*2+1][reg] = c * rn;
                }
    }

    #pragma unroll
    for (int fm = 0; fm < 4; ++fm) {
        int rbase = m0 + wm * 64 + fm * 16 + fh * 4;
        #pragma unroll
        for (int fn = 0; fn < 4; ++fn) {
            int col = n0 + wn * 64 + fn * 16 + fl;
            int hh  = (col >> 5) & 15;
            int idx = col & 31;
            float bb = (blk == 3) ? bias[col - 3 * HN] : 0.0f;
            #pragma unroll
            for (int reg = 0; reg < 4; ++reg) {
                float v = acc[fm][fn][reg];
                EPI_STORE(C, rbase, reg, hh, idx, blk, v, bb);
            }
        }
    }
}

// ---------- sequential recurrence (R9-proven 248us floor; do not touch) ----------
__global__ __launch_bounds__(256)
void recur(const float* __restrict__ proj, const float* __restrict__ S0,
           float* __restrict__ out, float* __restrict__ Sfin)
{
    const int tid = threadIdx.x;
    const int bx  = blockIdx.x;
    const int bh  = bx >> 1;                       // chain 0..127
    const int b   = bh >> 4, h = bh & 15;
    const int i   = ((bx & 1) << 4) + (tid >> 4);  // state row 0..31
    const int jl  = tid & 15;                      // owns j = 2jl, 2jl+1

    f32x2 S;
    {
        const float* s0p = S0 + (size_t)bh * 1024 + i * 32 + 2 * jl;
        S[0] = s0p[0]; S[1] = s0p[1];
    }

    const char* pkq = (const char*)proj + (size_t)b * 8192 + h * 512 + jl * 8;
    const char* pvb = (const char*)proj + (size_t)b * 8192 + h * 512 + 256 + i * 4;
    const size_t rstep = (size_t)BB * 8192;        // 65536 B per t

    f32x2 K2[PF], Q2[PF];
    float V[PF], Bt[PF];

    #pragma unroll
    for (int p = 0; p < PF; ++p) {
        asm volatile("global_load_dwordx2 %0, %1, off"            : "=v"(K2[p]) : "v"(pkq));
        asm volatile("global_load_dwordx2 %0, %1, off offset:128" : "=v"(Q2[p]) : "v"(pkq));
        asm volatile("global_load_dword %0, %1, off"              : "=v"(V[p])  : "v"(pvb));
        asm volatile("global_load_dword %0, %1, off offset:128"   : "=v"(Bt[p]) : "v"(pvb));
        pkq += rstep; pvb += rstep;
    }

    asm volatile("s_waitcnt vmcnt(28)" : "+v"(V[0]), "+v"(Bt[0]));
    float cv = V[0];
    f32x2 bS = Bt[0] * S;

    float* pout = out + (size_t)b * HN + h * 32 + i;   // stored when jl==0

    for (int t0 = 0; t0 < TT; t0 += PF) {
        float osave[PF];
        #pragma unroll
        for (int p = 0; p < PF; ++p) {
            const int pn = (p + 1) & (PF - 1);
            asm volatile("s_waitcnt vmcnt(24)"
                : "+v"(K2[p]), "+v"(Q2[p]), "+v"(V[pn]), "+v"(Bt[pn]));

            f32x2 k2 = K2[p];
            float rr = __builtin_fmaf(S[1], k2[1], S[0] * k2[0]);
            rr = reduce16(rr);
            float d = cv - rr;
            f32x2 a = d * k2 + bS;
            f32x2 e; e[0] = fexp2(a[0]); e[1] = fexp2(a[1]);
            f32x2 e1 = e + 1.0f;
            f32x2 r; r[0] = frcp(e1[0]); r[1] = frcp(e1[1]);
            S = -2.0f * r + 1.0f;

            f32x2 q2 = Q2[p];
            osave[p] = __builtin_fmaf(S[1], q2[1], S[0] * q2[0]);

            cv = V[pn];
            bS = Bt[pn] * S;

            asm volatile("global_load_dwordx2 %0, %1, off"            : "=v"(K2[p]) : "v"(pkq));
            asm volatile("global_load_dwordx2 %0, %1, off offset:128" : "=v"(Q2[p]) : "v"(pkq));
            asm volatile("global_load_dword %0, %1, off"              : "=v"(V[p])  : "v"(pvb));
            asm volatile("global_load_dword %0, %1, off offset:128"   : "=v"(Bt[p]) : "v"(pvb));
            pkq += rstep; pvb += rstep;
        }
        #pragma unroll
        for (int p = 0; p < PF; ++p) osave[p] = reduce16(osave[p]);
        if (jl == 0) {
            #pragma unroll
            for (int p = 0; p < PF; ++p) {
                float sq = osave[p];
                float sg = fast_sigmoid(sq);
                pout[(size_t)p * (BB * HN)] = sq * sq * sg;
            }
        }
        pout += (size_t)PF * (BB * HN);
    }

    {
        float* sf = Sfin + (size_t)bh * 1024 + i * 32 + 2 * jl;
        sf[0] = S[0]; sf[1] = S[1];
    }
}

extern "C" void kernel_launch(void* const* d_in, const int* in_sizes, int n_in,
                              void* d_out, int out_size, void* d_ws, size_t ws_size,
                              hipStream_t stream) {
    const float* x      = (const float*)d_in[0];
    const float* S0     = (const float*)d_in[1];
    const float* W_in   = (const float*)d_in[2];
    const float* W_k    = (const float*)d_in[3];
    const float* W_v    = (const float*)d_in[4];
    const float* W_q    = (const float*)d_in[5];
    const float* W_beta = (const float*)d_in[6];
    const float* b_beta = (const float*)d_in[7];

    float* ws   = (float*)d_ws;
    float* out_ = (float*)d_out;                  // [T,B,512]
    float* Sfin = out_ + (size_t)TT * BB * HN;    // [B,H,N,N]

    const size_t NEED_PRE = (size_t)(33554432 + 16777216 + 2*2097152) * 4; // 226.5 MB
    const bool pre = (ws_size >= NEED_PRE);

    if (pre) {
        float* proj   = ws;                         // 134 MB (packet layout)
        char*  xsplit = (char*)(ws + 33554432);     // 33.5 MB used (A single fp16)
        float* Weff   = ws + 33554432 + 16777216;   // 8 MB
        char*  wsplit = (char*)(Weff + 2097152);    // 4 MB (B single fp16)

        hipError_t aerr = hipFuncSetAttribute(
            reinterpret_cast<const void*>(&gemm_mfma8),
            hipFuncAttributeMaxDynamicSharedMemorySize, 65536);

        gemm_f32c<<<dim3(16, 32), dim3(256), 0, stream>>>(W_k, W_v, W_q, W_beta, W_in, Weff);
        wconv2<<<dim3(512), dim3(256), 0, stream>>>(Weff, wsplit);  // weights -> single fp16
        wconv2<<<dim3(4096), dim3(256), 0, stream>>>(x, xsplit);    // x -> single fp16
        if (aerr == hipSuccess) {
            gemm_mfma8<<<dim3(512), dim3(512), 65536, stream>>>(xsplit, wsplit, proj, b_beta);
        } else {
            gemm_mfma<<<dim3(2048), dim3(256), 0, stream>>>(x, wsplit, proj, b_beta);
        }
        recur<<<dim3(256), dim3(256), 0, stream>>>(proj, S0, out_, Sfin);
    } else {
        float* proj   = ws;
        float* Weff   = ws + 33554432;
        char*  wsplit = (char*)(Weff + 2097152);

        gemm_f32c<<<dim3(16, 32), dim3(256), 0, stream>>>(W_k, W_v, W_q, W_beta, W_in, Weff);
        wconv2<<<dim3(512), dim3(256), 0, stream>>>(Weff, wsplit);
        gemm_mfma<<<dim3(2048), dim3(256), 0, stream>>>(x, wsplit, proj, b_beta);
        recur<<<dim3(256), dim3(256), 0, stream>>>(proj, S0, out_, Sfin);
    }
}